// Round 14
// baseline (381.263 us; speedup 1.0000x reference)
//
#include <hip/hip_runtime.h>
#include <hip/hip_bf16.h>

// Problem constants
#define BB   64
#define CIN  3
#define HH   224
#define WW   224
#define C1   32
#define H1   112
#define W1   112
#define C2   64
#define H2   56
#define W2   56
#define FEATN 64
#define OUTN 1024
#define K3TOT (FEATN*FEATN*FEATN)   // 262144

typedef __bf16 bf16x8 __attribute__((ext_vector_type(8)));
typedef float  f32x4  __attribute__((ext_vector_type(4)));
typedef unsigned int u32;

__device__ __forceinline__ void gload_lds16(const void* g, void* l) {
  __builtin_amdgcn_global_load_lds((const __attribute__((address_space(1))) u32*)g,
                                   (__attribute__((address_space(3))) u32*)l, 16, 0, 0);
}
// non-temporal variant for single-use streams (w3)
__device__ __forceinline__ void gload_lds16_nt(const void* g, void* l) {
  __builtin_amdgcn_global_load_lds((const __attribute__((address_space(1))) u32*)g,
                                   (__attribute__((address_space(3))) u32*)l, 16, 0, 2);
}

// ---------------- conv1 (+ merged prep): halo, w2frag, conv -------------------
__global__ __launch_bounds__(256) void conv1_kernel(const float* __restrict__ x,
        const float* __restrict__ w1, const float* __restrict__ b1,
        __bf16* __restrict__ h1T, const float* __restrict__ w2,
        __bf16* __restrict__ wf) {
    int gid = blockIdx.x * 256 + threadIdx.x;

    // ---- prep section (blocks 0..184): halo-zero + w2frag
    if (gid < 64 * 452) {
      int b = gid / 452, s = gid - b * 452;
      int row, col;
      if      (s < 114) { row = 0;        col = s; }
      else if (s < 228) { row = 113;      col = s - 114; }
      else if (s < 340) { row = s - 227;  col = 0; }
      else              { row = s - 339;  col = 113; }
      __bf16* p = h1T + (((size_t)b * 114 + row) * 114 + col) * 32;
      bf16x8 z = {};
      #pragma unroll
      for (int k = 0; k < 4; ++k) *(bf16x8*)(p + k * 8) = z;
    } else if (gid < 64 * 452 + 18432) {
      int t = gid - 64 * 452;
      int e    = t & 7;
      int lane = (t >> 3) & 63;
      int q    = (t >> 9) % 9;
      int j    = t / 4608;
      int oc = j * 16 + (lane & 15);
      int c  = (lane >> 4) * 8 + e;
      wf[t] = (__bf16)w2[(oc * C1 + c) * 9 + q];
    }

    // ---- conv section (all blocks): 2 outputs/thread, float4 row loads
    int pos = gid;                                   // 64*112*56 = 401408
    int b   = pos / (H1 * 56);
    int rem = pos - b * (H1 * 56);
    int oy  = rem / 56;
    int g   = rem - oy * 56;                         // x-pair group: ox = 2g+u
    int iy0 = oy * 2 - 1;

    float win[CIN][3][5];
    #pragma unroll
    for (int c = 0; c < CIN; ++c)
      #pragma unroll
      for (int dy = 0; dy < 3; ++dy) {
        int iy = iy0 + dy;
        bool rv = (iy >= 0) & (iy < HH);
        const float* row = x + ((size_t)(b * CIN + c) * HH + (rv ? iy : 0)) * WW;
        float lf = (rv && g > 0) ? row[4 * g - 1] : 0.f;
        float4 f4 = rv ? *(const float4*)(row + 4 * g) : (float4){0.f, 0.f, 0.f, 0.f};
        win[c][dy][0] = lf;
        win[c][dy][1] = f4.x; win[c][dy][2] = f4.y;
        win[c][dy][3] = f4.z; win[c][dy][4] = f4.w;
      }

    float acc[2][C1];
    #pragma unroll
    for (int u = 0; u < 2; ++u)
      #pragma unroll
      for (int oc = 0; oc < C1; ++oc) acc[u][oc] = b1[oc];

    #pragma unroll
    for (int c = 0; c < CIN; ++c)
      #pragma unroll
      for (int dy = 0; dy < 3; ++dy)
        #pragma unroll
        for (int dx = 0; dx < 3; ++dx) {
          float w0 = win[c][dy][dx];
          float w1v = win[c][dy][dx + 2];
          const float* wq = w1 + c * 9 + dy * 3 + dx;
          #pragma unroll
          for (int oc = 0; oc < C1; ++oc) {
            float wv = wq[oc * 27];
            acc[0][oc] = fmaf(wv, w0, acc[0][oc]);
            acc[1][oc] = fmaf(wv, w1v, acc[1][oc]);
          }
        }

    __bf16* dst = h1T + (((size_t)b * 114 + oy + 1) * 114 + (2 * g) + 1) * 32;
    #pragma unroll
    for (int u = 0; u < 2; ++u) {
      bf16x8 outv[4];
      #pragma unroll
      for (int k = 0; k < 32; ++k)
        outv[k >> 3][k & 7] = (__bf16)fmaxf(acc[u][k], 0.f);
      #pragma unroll
      for (int k = 0; k < 4; ++k) *(bf16x8*)(dst + u * 32 + k * 8) = outv[k];
    }
}

// ------ conv2 + fused global-avg-pool: implicit-GEMM MFMA, partials out -------
__global__ __launch_bounds__(256) void conv2_kernel(const __bf16* __restrict__ h1T,
        const __bf16* __restrict__ wf, const float* __restrict__ b2,
        float* __restrict__ featp) {
    __shared__ __align__(16) char tile[2304 * 16];   // 36864 B
    __shared__ float pool_red[4][64];
    int t = threadIdx.x;
    int bid = blockIdx.x;                            // 64*28 = 1792
    int b  = bid / 28;
    int yt = bid - b * 28;
    int y0 = yt * 2;
    int w = t >> 6, lane = t & 63, l15 = lane & 15, l4 = lane >> 4;

    const char* src_base = (const char*)(h1T + ((size_t)b * 114 + 2 * y0) * 114 * 32);
    #pragma unroll
    for (int i = 0; i < 9; ++i) {
      int g = (w * 9 + i) * 64 + lane;
      int site = g >> 2; site = site < 569 ? site : 569;
      int qp = g & 3;
      int r5 = site / 114;
      int col = site - r5 * 114;
      int ql = (qp - col) & 3;
      gload_lds16(src_base + (size_t)site * 64 + ql * 16, tile + (size_t)g * 16);
    }
    __syncthreads();

    int sbase[2], urot[2];
    #pragma unroll
    for (int p = 0; p < 2; ++p) {
      int mt = 2 * w + p;
      int yl = mt >> 2;
      int xl = ((mt & 3) << 4) + l15;
      int xe = xl < 55 ? xl : 55;
      sbase[p] = ((yl * 2) * 114 + 2 * xe) * 64;
      urot[p]  = (l4 + 2 * xe) & 3;
    }

    f32x4 acc[2][4];
    #pragma unroll
    for (int p = 0; p < 2; ++p)
      #pragma unroll
      for (int j = 0; j < 4; ++j) acc[p][j] = (f32x4){0.f, 0.f, 0.f, 0.f};

    #pragma unroll
    for (int q = 0; q < 9; ++q) {
      int dy = q / 3, dx = q % 3;
      bf16x8 bw[4];
      #pragma unroll
      for (int j = 0; j < 4; ++j)
        bw[j] = *(const bf16x8*)(wf + ((j * 9 + q) * 64 + lane) * 8);
      bf16x8 af[2];
      #pragma unroll
      for (int p = 0; p < 2; ++p) {
        int addr = sbase[p] + (dy * 114 + dx) * 64 + (((urot[p] + dx) & 3) << 4);
        af[p] = *(const bf16x8*)(tile + addr);
      }
      #pragma unroll
      for (int p = 0; p < 2; ++p)
        #pragma unroll
        for (int j = 0; j < 4; ++j)
          acc[p][j] = __builtin_amdgcn_mfma_f32_16x16x32_bf16(af[p], bw[j], acc[p][j], 0, 0, 0);
    }

    float bias[4];
    #pragma unroll
    for (int j = 0; j < 4; ++j) bias[j] = b2[j * 16 + l15];
    float ps[4] = {0.f, 0.f, 0.f, 0.f};
    #pragma unroll
    for (int p = 0; p < 2; ++p) {
      int mt = 2 * w + p;
      bool valid = ((mt & 3) != 3) || (l4 < 2);      // x<56 mask
      #pragma unroll
      for (int j = 0; j < 4; ++j) {
        float sj = 0.f;
        #pragma unroll
        for (int r = 0; r < 4; ++r)
          sj += fmaxf(acc[p][j][r] + bias[j], 0.f);
        ps[j] += valid ? sj : 0.f;
      }
    }
    #pragma unroll
    for (int j = 0; j < 4; ++j) {
      ps[j] += __shfl_xor(ps[j], 16);
      ps[j] += __shfl_xor(ps[j], 32);
    }
    if (l4 == 0) {
      #pragma unroll
      for (int j = 0; j < 4; ++j) pool_red[w][j * 16 + l15] = ps[j];
    }
    __syncthreads();
    if (t < 64) {
      float s = pool_red[0][t] + pool_red[1][t] + pool_red[2][t] + pool_red[3][t];
      featp[((size_t)yt * 64 + b) * 64 + t] = s;
    }
}

// ---- center2: featN = (sum_yt featp)/3136; fc = featN - rowmean(featN) -------
__global__ __launch_bounds__(64) void center2_kernel(const float* __restrict__ featp,
        float* __restrict__ featN, float* __restrict__ fc) {
    int b = blockIdx.x;                              // 64 blocks (1 wave each)
    int c = threadIdx.x;
    float s = 0.f;
    #pragma unroll 7
    for (int yt = 0; yt < 28; ++yt)
      s += featp[((size_t)yt * 64 + b) * 64 + c];
    s *= (1.f / (H2 * W2));
    float tot = s;
    #pragma unroll
    for (int off = 32; off; off >>= 1) tot += __shfl_xor(tot, off);
    featN[b * 64 + c] = s;
    fc[b * 64 + c]    = s - tot * (1.f / 64.f);
}

// -------- third-order term, ONE WAVE = ONE FULL w3 ROW -------------------------
// Block = 2 waves; wave w streams row o = 2*bid + w: 1 MB contiguous, 256 x 4KB
// chunks via global_load_lds (pre-swizzled source, linear dest, swizzled read),
// double-buffered, counted vmcnt, zero barriers in the loop. Grid 512 = 2
// blocks/CU: ALL resident, single uniform pass, no tail, no cross-wave reduce.
#define T3_NCH 256          // chunks per row (1MB / 4KB)

struct T3S {
    float stage[2][2][16][64];   // [wave][buf][ij][k]  32 KB
    float fcT[64][66];           // fcT[c][b], padded   16.9 KB
};

__global__ __launch_bounds__(128) void third_kernel(const float* __restrict__ fc,
        const float* __restrict__ w3, float* __restrict__ thrd) {
    __shared__ __align__(16) T3S sh;
    int t = threadIdx.x;
    int w = t >> 6, lane = t & 63, l15 = lane & 15, l4 = lane >> 4;
    int o = blockIdx.x * 2 + w;
    int swz = (l15 & 7) << 4;

    const char* seg = (const char*)w3 + ((size_t)o << 20);

    // issue chunk 0 first (HBM starts immediately)
    #pragma unroll
    for (int ii = 0; ii < 4; ++ii) {
      int row = ii * 4 + l4;
      int lo  = l15 * 16;
      gload_lds16_nt(seg + row * 256 + (lo ^ ((row & 7) << 4)),
                     (char*)&sh.stage[w][0][0][0] + ii * 1024);
    }

    // stage fcT[c][b] = fc[b*64+c]
    for (int idx = t; idx < 4096; idx += 128)
      sh.fcT[idx & 63][idx >> 6] = fc[idx];

    // B-fragments in registers: bfrag[ks][nt] = fc[b=nt*16+l15][ks*32+l4*8+e]
    bf16x8 bfrag[2][4];
    #pragma unroll
    for (int ks = 0; ks < 2; ++ks)
      #pragma unroll
      for (int nt = 0; nt < 4; ++nt) {
        const float* p = fc + (nt * 16 + l15) * 64 + ks * 32 + l4 * 8;
        float4 v0 = *(const float4*)p;
        float4 v1 = *(const float4*)(p + 4);
        bfrag[ks][nt][0] = (__bf16)v0.x; bfrag[ks][nt][1] = (__bf16)v0.y;
        bfrag[ks][nt][2] = (__bf16)v0.z; bfrag[ks][nt][3] = (__bf16)v0.w;
        bfrag[ks][nt][4] = (__bf16)v1.x; bfrag[ks][nt][5] = (__bf16)v1.y;
        bfrag[ks][nt][6] = (__bf16)v1.z; bfrag[ks][nt][7] = (__bf16)v1.w;
      }

    __syncthreads();                                 // fcT + chunk0 ready

    float oacc[4] = {0.f, 0.f, 0.f, 0.f};

    #pragma unroll 1
    for (int c = 0; c < T3_NCH; ++c) {
      if (c + 1 < T3_NCH) {
        const char* s2 = seg + (size_t)(c + 1) * 4096;
        char* db = (char*)&sh.stage[w][(c + 1) & 1][0][0];
        #pragma unroll
        for (int ii = 0; ii < 4; ++ii) {
          int row = ii * 4 + l4;
          int lo  = l15 * 16;
          gload_lds16_nt(s2 + row * 256 + (lo ^ ((row & 7) << 4)), db + ii * 1024);
        }
        asm volatile("s_waitcnt vmcnt(4)" ::: "memory");
      } else {
        asm volatile("s_waitcnt vmcnt(0)" ::: "memory");
      }
      __builtin_amdgcn_sched_barrier(0);

      // ---- compute chunk c: v[ij,b] = sum_k w3chunk[ij,k] fc[b,k]
      const char* cb = (const char*)&sh.stage[w][c & 1][0][0];
      f32x4 acc[4];
      #pragma unroll
      for (int nt = 0; nt < 4; ++nt) acc[nt] = (f32x4){0.f, 0.f, 0.f, 0.f};
      #pragma unroll
      for (int ks = 0; ks < 2; ++ks) {
        int off0 = l15 * 256 + ((ks * 128 + l4 * 32) ^ swz);
        float4 a0 = *(const float4*)(cb + off0);
        float4 a1 = *(const float4*)(cb + (off0 ^ 16));
        bf16x8 af;
        af[0] = (__bf16)a0.x; af[1] = (__bf16)a0.y;
        af[2] = (__bf16)a0.z; af[3] = (__bf16)a0.w;
        af[4] = (__bf16)a1.x; af[5] = (__bf16)a1.y;
        af[6] = (__bf16)a1.z; af[7] = (__bf16)a1.w;
        #pragma unroll
        for (int nt = 0; nt < 4; ++nt)
          acc[nt] = __builtin_amdgcn_mfma_f32_16x16x32_bf16(af, bfrag[ks][nt], acc[nt], 0, 0, 0);
      }
      // contraction: oacc[b] += fc_i[b] * sum_r fc_j(r)[b] * v[r][b]
      int i = c >> 2;                                // uniform within chunk
      #pragma unroll
      for (int nt = 0; nt < 4; ++nt) {
        int b = nt * 16 + l15;
        float s = 0.f;
        #pragma unroll
        for (int r = 0; r < 4; ++r) {
          int j = (c * 16 + l4 * 4 + r) & 63;
          s = fmaf(sh.fcT[j][b], acc[nt][r], s);
        }
        oacc[nt] = fmaf(sh.fcT[i][b], s, oacc[nt]);
      }
    }

    // reduce over l4 groups (ij rows); each wave writes its own output row
    #pragma unroll
    for (int nt = 0; nt < 4; ++nt) {
      oacc[nt] += __shfl_xor(oacc[nt], 16);
      oacc[nt] += __shfl_xor(oacc[nt], 32);
    }
    if (l4 == 0) {
      #pragma unroll
      for (int nt = 0; nt < 4; ++nt)
        thrd[o * 64 + nt * 16 + l15] = oacc[nt];
    }
}

// ---- finale: mean_feat + cov_feat + biases + third -> d_out ------------------
__global__ __launch_bounds__(256) void finale_kernel(const float* __restrict__ feat,
        const float* __restrict__ fc,
        const float* __restrict__ wm, const float* __restrict__ bm,
        const float* __restrict__ wc, const float* __restrict__ bcv,
        const float* __restrict__ b3, const float* __restrict__ thrd,
        float* __restrict__ out) {
    __shared__ float featT[FEATN * FEATN];           // [c][b]
    __shared__ float fcT[FEATN * FEATN];             // [c][b]
    int t = threadIdx.x;
    for (int i = t; i < FEATN * FEATN; i += 256) {
      int b = i >> 6, c = i & 63;
      featT[c*64 + b] = feat[i];
      fcT[c*64 + b]   = fc[i];
    }
    __syncthreads();

    int b = t & 63;
    int o = blockIdx.x * 4 + (t >> 6);               // 256 blocks * 4 = 1024

    float fr[64];                                    // fc[b][*] in registers
    #pragma unroll
    for (int c4 = 0; c4 < 16; ++c4) {
      float4 v = *(const float4*)(fc + b*64 + c4*4);
      fr[c4*4+0]=v.x; fr[c4*4+1]=v.y; fr[c4*4+2]=v.z; fr[c4*4+3]=v.w;
    }

    float acc = bm[o] + bcv[o] + b3[o];
    #pragma unroll 8
    for (int c = 0; c < FEATN; ++c)
      acc = fmaf(featT[c*64 + b], wm[o*FEATN + c], acc);

    const float* wcrow = wc + (size_t)o * (FEATN * FEATN);
    #pragma unroll 1
    for (int c1 = 0; c1 < 64; ++c1) {
      float a2 = 0.f;
      #pragma unroll
      for (int c2 = 0; c2 < 64; ++c2)                // fr[c2]: static index
        a2 = fmaf(fr[c2], wcrow[c1*64 + c2], a2);
      acc = fmaf(fcT[c1*64 + b], a2, acc);
    }

    out[b * OUTN + o] = acc + thrd[o * 64 + b];
}

extern "C" void kernel_launch(void* const* d_in, const int* in_sizes, int n_in,
                              void* d_out, int out_size, void* d_ws, size_t ws_size,
                              hipStream_t stream) {
    const float* x   = (const float*)d_in[0];
    const float* w1  = (const float*)d_in[1];
    const float* b1  = (const float*)d_in[2];
    const float* w2  = (const float*)d_in[3];
    const float* b2  = (const float*)d_in[4];
    const float* wm  = (const float*)d_in[5];
    const float* bm  = (const float*)d_in[6];
    const float* wc  = (const float*)d_in[7];
    const float* bcv = (const float*)d_in[8];
    const float* w3  = (const float*)d_in[9];
    const float* b3  = (const float*)d_in[10];
    float* out = (float*)d_out;

    // workspace layout (float offsets):
    //   h1T (bf16) | featp | featN | fc | thrd | w2frag
    float* ws    = (float*)d_ws;
    __bf16* h1T  = (__bf16*)ws;                      // 26,615,808 bf16 = 53.2 MB
    float* featp = ws + 13307904;                    // 28*64*64 = 114,688
    float* featN = ws + 13422592;                    // 4096
    float* fcv   = ws + 13426688;                    // 4096
    float* thrd  = ws + 13430784;                    // 64*1024 = 65,536
    __bf16* wfrg = (__bf16*)(ws + 13496320);         // 18,432 bf16

    conv1_kernel  <<<1568, 256, 0, stream>>>(x, w1, b1, h1T, w2, wfrg);
    conv2_kernel  <<<1792, 256, 0, stream>>>(h1T, wfrg, b2, featp);
    center2_kernel<<<64,   64,  0, stream>>>(featp, featN, fcv);
    third_kernel  <<<512,  128, 0, stream>>>(fcv, w3, thrd);
    finale_kernel <<<256,  256, 0, stream>>>(featN, fcv, wm, bm, wc, bcv, b3, thrd, out);
}

// Round 15
// 290.965 us; speedup vs baseline: 1.3103x; 1.3103x over previous
//
#include <hip/hip_runtime.h>
#include <hip/hip_bf16.h>

// Problem constants
#define BB   64
#define CIN  3
#define HH   224
#define WW   224
#define C1   32
#define H1   112
#define W1   112
#define C2   64
#define H2   56
#define W2   56
#define FEATN 64
#define OUTN 1024
#define K3TOT (FEATN*FEATN*FEATN)   // 262144

typedef __bf16 bf16x8 __attribute__((ext_vector_type(8)));
typedef float  f32x4  __attribute__((ext_vector_type(4)));
typedef unsigned int u32;

__device__ __forceinline__ void gload_lds16(const void* g, void* l) {
  __builtin_amdgcn_global_load_lds((const __attribute__((address_space(1))) u32*)g,
                                   (__attribute__((address_space(3))) u32*)l, 16, 0, 0);
}
// non-temporal variant for single-use streams (w3)
__device__ __forceinline__ void gload_lds16_nt(const void* g, void* l) {
  __builtin_amdgcn_global_load_lds((const __attribute__((address_space(1))) u32*)g,
                                   (__attribute__((address_space(3))) u32*)l, 16, 0, 2);
}

// ---------------- conv1 (+ merged prep): halo, w2frag, conv -------------------
__global__ __launch_bounds__(256) void conv1_kernel(const float* __restrict__ x,
        const float* __restrict__ w1, const float* __restrict__ b1,
        __bf16* __restrict__ h1T, const float* __restrict__ w2,
        __bf16* __restrict__ wf) {
    int gid = blockIdx.x * 256 + threadIdx.x;

    // ---- prep section (blocks 0..184): halo-zero + w2frag
    if (gid < 64 * 452) {
      int b = gid / 452, s = gid - b * 452;
      int row, col;
      if      (s < 114) { row = 0;        col = s; }
      else if (s < 228) { row = 113;      col = s - 114; }
      else if (s < 340) { row = s - 227;  col = 0; }
      else              { row = s - 339;  col = 113; }
      __bf16* p = h1T + (((size_t)b * 114 + row) * 114 + col) * 32;
      bf16x8 z = {};
      #pragma unroll
      for (int k = 0; k < 4; ++k) *(bf16x8*)(p + k * 8) = z;
    } else if (gid < 64 * 452 + 18432) {
      int t = gid - 64 * 452;
      int e    = t & 7;
      int lane = (t >> 3) & 63;
      int q    = (t >> 9) % 9;
      int j    = t / 4608;
      int oc = j * 16 + (lane & 15);
      int c  = (lane >> 4) * 8 + e;
      wf[t] = (__bf16)w2[(oc * C1 + c) * 9 + q];
    }

    // ---- conv section (all blocks): 2 outputs/thread, float4 row loads
    int pos = gid;                                   // 64*112*56 = 401408
    int b   = pos / (H1 * 56);
    int rem = pos - b * (H1 * 56);
    int oy  = rem / 56;
    int g   = rem - oy * 56;                         // x-pair group: ox = 2g+u
    int iy0 = oy * 2 - 1;

    float win[CIN][3][5];
    #pragma unroll
    for (int c = 0; c < CIN; ++c)
      #pragma unroll
      for (int dy = 0; dy < 3; ++dy) {
        int iy = iy0 + dy;
        bool rv = (iy >= 0) & (iy < HH);
        const float* row = x + ((size_t)(b * CIN + c) * HH + (rv ? iy : 0)) * WW;
        float lf = (rv && g > 0) ? row[4 * g - 1] : 0.f;
        float4 f4 = rv ? *(const float4*)(row + 4 * g) : (float4){0.f, 0.f, 0.f, 0.f};
        win[c][dy][0] = lf;
        win[c][dy][1] = f4.x; win[c][dy][2] = f4.y;
        win[c][dy][3] = f4.z; win[c][dy][4] = f4.w;
      }

    float acc[2][C1];
    #pragma unroll
    for (int u = 0; u < 2; ++u)
      #pragma unroll
      for (int oc = 0; oc < C1; ++oc) acc[u][oc] = b1[oc];

    #pragma unroll
    for (int c = 0; c < CIN; ++c)
      #pragma unroll
      for (int dy = 0; dy < 3; ++dy)
        #pragma unroll
        for (int dx = 0; dx < 3; ++dx) {
          float w0 = win[c][dy][dx];
          float w1v = win[c][dy][dx + 2];
          const float* wq = w1 + c * 9 + dy * 3 + dx;
          #pragma unroll
          for (int oc = 0; oc < C1; ++oc) {
            float wv = wq[oc * 27];
            acc[0][oc] = fmaf(wv, w0, acc[0][oc]);
            acc[1][oc] = fmaf(wv, w1v, acc[1][oc]);
          }
        }

    __bf16* dst = h1T + (((size_t)b * 114 + oy + 1) * 114 + (2 * g) + 1) * 32;
    #pragma unroll
    for (int u = 0; u < 2; ++u) {
      bf16x8 outv[4];
      #pragma unroll
      for (int k = 0; k < 32; ++k)
        outv[k >> 3][k & 7] = (__bf16)fmaxf(acc[u][k], 0.f);
      #pragma unroll
      for (int k = 0; k < 4; ++k) *(bf16x8*)(dst + u * 32 + k * 8) = outv[k];
    }
}

// ------ conv2 + fused global-avg-pool: implicit-GEMM MFMA, partials out -------
__global__ __launch_bounds__(256) void conv2_kernel(const __bf16* __restrict__ h1T,
        const __bf16* __restrict__ wf, const float* __restrict__ b2,
        float* __restrict__ featp) {
    __shared__ __align__(16) char tile[2304 * 16];   // 36864 B
    __shared__ float pool_red[4][64];
    int t = threadIdx.x;
    int bid = blockIdx.x;                            // 64*28 = 1792
    int b  = bid / 28;
    int yt = bid - b * 28;
    int y0 = yt * 2;
    int w = t >> 6, lane = t & 63, l15 = lane & 15, l4 = lane >> 4;

    const char* src_base = (const char*)(h1T + ((size_t)b * 114 + 2 * y0) * 114 * 32);
    #pragma unroll
    for (int i = 0; i < 9; ++i) {
      int g = (w * 9 + i) * 64 + lane;
      int site = g >> 2; site = site < 569 ? site : 569;
      int qp = g & 3;
      int r5 = site / 114;
      int col = site - r5 * 114;
      int ql = (qp - col) & 3;
      gload_lds16(src_base + (size_t)site * 64 + ql * 16, tile + (size_t)g * 16);
    }
    __syncthreads();

    int sbase[2], urot[2];
    #pragma unroll
    for (int p = 0; p < 2; ++p) {
      int mt = 2 * w + p;
      int yl = mt >> 2;
      int xl = ((mt & 3) << 4) + l15;
      int xe = xl < 55 ? xl : 55;
      sbase[p] = ((yl * 2) * 114 + 2 * xe) * 64;
      urot[p]  = (l4 + 2 * xe) & 3;
    }

    f32x4 acc[2][4];
    #pragma unroll
    for (int p = 0; p < 2; ++p)
      #pragma unroll
      for (int j = 0; j < 4; ++j) acc[p][j] = (f32x4){0.f, 0.f, 0.f, 0.f};

    #pragma unroll
    for (int q = 0; q < 9; ++q) {
      int dy = q / 3, dx = q % 3;
      bf16x8 bw[4];
      #pragma unroll
      for (int j = 0; j < 4; ++j)
        bw[j] = *(const bf16x8*)(wf + ((j * 9 + q) * 64 + lane) * 8);
      bf16x8 af[2];
      #pragma unroll
      for (int p = 0; p < 2; ++p) {
        int addr = sbase[p] + (dy * 114 + dx) * 64 + (((urot[p] + dx) & 3) << 4);
        af[p] = *(const bf16x8*)(tile + addr);
      }
      #pragma unroll
      for (int p = 0; p < 2; ++p)
        #pragma unroll
        for (int j = 0; j < 4; ++j)
          acc[p][j] = __builtin_amdgcn_mfma_f32_16x16x32_bf16(af[p], bw[j], acc[p][j], 0, 0, 0);
    }

    float bias[4];
    #pragma unroll
    for (int j = 0; j < 4; ++j) bias[j] = b2[j * 16 + l15];
    float ps[4] = {0.f, 0.f, 0.f, 0.f};
    #pragma unroll
    for (int p = 0; p < 2; ++p) {
      int mt = 2 * w + p;
      bool valid = ((mt & 3) != 3) || (l4 < 2);      // x<56 mask
      #pragma unroll
      for (int j = 0; j < 4; ++j) {
        float sj = 0.f;
        #pragma unroll
        for (int r = 0; r < 4; ++r)
          sj += fmaxf(acc[p][j][r] + bias[j], 0.f);
        ps[j] += valid ? sj : 0.f;
      }
    }
    #pragma unroll
    for (int j = 0; j < 4; ++j) {
      ps[j] += __shfl_xor(ps[j], 16);
      ps[j] += __shfl_xor(ps[j], 32);
    }
    if (l4 == 0) {
      #pragma unroll
      for (int j = 0; j < 4; ++j) pool_red[w][j * 16 + l15] = ps[j];
    }
    __syncthreads();
    if (t < 64) {
      float s = pool_red[0][t] + pool_red[1][t] + pool_red[2][t] + pool_red[3][t];
      featp[((size_t)yt * 64 + b) * 64 + t] = s;
    }
}

// ---- center2: featN = (sum_yt featp)/3136; fc = featN - rowmean(featN) -------
__global__ __launch_bounds__(64) void center2_kernel(const float* __restrict__ featp,
        float* __restrict__ featN, float* __restrict__ fc) {
    int b = blockIdx.x;                              // 64 blocks (1 wave each)
    int c = threadIdx.x;
    float s = 0.f;
    #pragma unroll 7
    for (int yt = 0; yt < 28; ++yt)
      s += featp[((size_t)yt * 64 + b) * 64 + c];
    s *= (1.f / (H2 * W2));
    float tot = s;
    #pragma unroll
    for (int off = 32; off; off >>= 1) tot += __shfl_xor(tot, off);
    featN[b * 64 + c] = s;
    fc[b * 64 + c]    = s - tot * (1.f / 64.f);
}

// -------- third-order term, ROW-STREAM (exact R12 config: 188us, 5.7TB/s) -----
// One block per output column o; 2 waves x 512 KB halves, 4 KB chunks via
// global_load_lds (pre-swizzled source, linear dest, swizzled read), dbuf,
// counted vmcnt, no barriers in loop. Grid 1024 @ 3 blocks/CU (6 waves/CU).
#define T3_NCH 128          // chunks per wave (512KB / 4KB)

struct T3S {
    float stage[2][2][16][64];   // [wave][buf][ij][k]  32 KB
    float fcT[64][66];           // fcT[c][b], padded   16.9 KB
    float wred[2][64];
};

__global__ __launch_bounds__(128) void third_kernel(const float* __restrict__ fc,
        const float* __restrict__ w3, float* __restrict__ thrd) {
    __shared__ __align__(16) T3S sh;
    int t = threadIdx.x;
    int w = t >> 6, lane = t & 63, l15 = lane & 15, l4 = lane >> 4;
    int o = blockIdx.x;
    int swz = (l15 & 7) << 4;

    // stage fcT[c][b] = fc[b*64+c]
    for (int idx = t; idx < 4096; idx += 128)
      sh.fcT[idx & 63][idx >> 6] = fc[idx];

    const char* seg = (const char*)w3 + ((size_t)o << 20) + (size_t)w * 524288;

    // issue chunk 0 early (overlaps fcT staging + B-frag loads)
    #pragma unroll
    for (int ii = 0; ii < 4; ++ii) {
      int row = ii * 4 + (lane >> 4);
      int lo  = (lane & 15) * 16;
      gload_lds16_nt(seg + row * 256 + (lo ^ ((row & 7) << 4)),
                     (char*)&sh.stage[w][0][0][0] + ii * 1024);
    }

    // B-fragments in registers: bfrag[kstep][ntile] = fc[b=nt*16+l15][ks*32+l4*8+e]
    bf16x8 bfrag[2][4];
    #pragma unroll
    for (int ks = 0; ks < 2; ++ks)
      #pragma unroll
      for (int nt = 0; nt < 4; ++nt) {
        const float* p = fc + (nt * 16 + l15) * 64 + ks * 32 + l4 * 8;
        float4 v0 = *(const float4*)p;
        float4 v1 = *(const float4*)(p + 4);
        bfrag[ks][nt][0] = (__bf16)v0.x; bfrag[ks][nt][1] = (__bf16)v0.y;
        bfrag[ks][nt][2] = (__bf16)v0.z; bfrag[ks][nt][3] = (__bf16)v0.w;
        bfrag[ks][nt][4] = (__bf16)v1.x; bfrag[ks][nt][5] = (__bf16)v1.y;
        bfrag[ks][nt][6] = (__bf16)v1.z; bfrag[ks][nt][7] = (__bf16)v1.w;
      }

    __syncthreads();                                 // fcT ready (drains vmcnt too)

    float oacc[4] = {0.f, 0.f, 0.f, 0.f};

    #pragma unroll 1
    for (int c = 0; c < T3_NCH; ++c) {
      // issue chunk c+1 into the other buffer
      if (c + 1 < T3_NCH) {
        const char* s2 = seg + (size_t)(c + 1) * 4096;
        char* db = (char*)&sh.stage[w][(c + 1) & 1][0][0];
        #pragma unroll
        for (int ii = 0; ii < 4; ++ii) {
          int row = ii * 4 + (lane >> 4);
          int lo  = (lane & 15) * 16;
          gload_lds16_nt(s2 + row * 256 + (lo ^ ((row & 7) << 4)), db + ii * 1024);
        }
        asm volatile("s_waitcnt vmcnt(4)" ::: "memory");
      } else {
        asm volatile("s_waitcnt vmcnt(0)" ::: "memory");
      }
      __builtin_amdgcn_sched_barrier(0);

      // ---- compute chunk c
      const char* cb = (const char*)&sh.stage[w][c & 1][0][0];
      f32x4 acc[4];
      #pragma unroll
      for (int nt = 0; nt < 4; ++nt) acc[nt] = (f32x4){0.f, 0.f, 0.f, 0.f};
      #pragma unroll
      for (int ks = 0; ks < 2; ++ks) {
        int off0 = l15 * 256 + ((ks * 128 + l4 * 32) ^ swz);
        float4 a0 = *(const float4*)(cb + off0);
        float4 a1 = *(const float4*)(cb + (off0 ^ 16));
        bf16x8 af;
        af[0] = (__bf16)a0.x; af[1] = (__bf16)a0.y;
        af[2] = (__bf16)a0.z; af[3] = (__bf16)a0.w;
        af[4] = (__bf16)a1.x; af[5] = (__bf16)a1.y;
        af[6] = (__bf16)a1.z; af[7] = (__bf16)a1.w;
        #pragma unroll
        for (int nt = 0; nt < 4; ++nt)
          acc[nt] = __builtin_amdgcn_mfma_f32_16x16x32_bf16(af, bfrag[ks][nt], acc[nt], 0, 0, 0);
      }
      // contraction: out[b] += fi[b] * sum_r fj(r)[b] * v[r][b]
      int i = w * 32 + (c >> 2);                     // uniform within chunk
      #pragma unroll
      for (int nt = 0; nt < 4; ++nt) {
        int b = nt * 16 + l15;
        float s = 0.f;
        #pragma unroll
        for (int r = 0; r < 4; ++r) {
          int j = (c * 16 + l4 * 4 + r) & 63;
          s = fmaf(sh.fcT[j][b], acc[nt][r], s);
        }
        oacc[nt] = fmaf(sh.fcT[i][b], s, oacc[nt]);
      }
    }

    // reduce over l4 (rows), then over waves
    #pragma unroll
    for (int nt = 0; nt < 4; ++nt) {
      oacc[nt] += __shfl_xor(oacc[nt], 16);
      oacc[nt] += __shfl_xor(oacc[nt], 32);
    }
    if (l4 == 0) {
      #pragma unroll
      for (int nt = 0; nt < 4; ++nt) sh.wred[w][nt * 16 + l15] = oacc[nt];
    }
    __syncthreads();
    if (t < 64) thrd[o * 64 + t] = sh.wred[0][t] + sh.wred[1][t];
}

// ---- finale: mean_feat + cov_feat + biases + third -> d_out ------------------
__global__ __launch_bounds__(256) void finale_kernel(const float* __restrict__ feat,
        const float* __restrict__ fc,
        const float* __restrict__ wm, const float* __restrict__ bm,
        const float* __restrict__ wc, const float* __restrict__ bcv,
        const float* __restrict__ b3, const float* __restrict__ thrd,
        float* __restrict__ out) {
    __shared__ float featT[FEATN * FEATN];           // [c][b]
    __shared__ float fcT[FEATN * FEATN];             // [c][b]
    int t = threadIdx.x;
    for (int i = t; i < FEATN * FEATN; i += 256) {
      int b = i >> 6, c = i & 63;
      featT[c*64 + b] = feat[i];
      fcT[c*64 + b]   = fc[i];
    }
    __syncthreads();

    int b = t & 63;
    int o = blockIdx.x * 4 + (t >> 6);               // 256 blocks * 4 = 1024

    float fr[64];                                    // fc[b][*] in registers
    #pragma unroll
    for (int c4 = 0; c4 < 16; ++c4) {
      float4 v = *(const float4*)(fc + b*64 + c4*4);
      fr[c4*4+0]=v.x; fr[c4*4+1]=v.y; fr[c4*4+2]=v.z; fr[c4*4+3]=v.w;
    }

    float acc = bm[o] + bcv[o] + b3[o];
    #pragma unroll 8
    for (int c = 0; c < FEATN; ++c)
      acc = fmaf(featT[c*64 + b], wm[o*FEATN + c], acc);

    const float* wcrow = wc + (size_t)o * (FEATN * FEATN);
    #pragma unroll 1
    for (int c1 = 0; c1 < 64; ++c1) {
      float a2 = 0.f;
      #pragma unroll
      for (int c2 = 0; c2 < 64; ++c2)                // fr[c2]: static index
        a2 = fmaf(fr[c2], wcrow[c1*64 + c2], a2);
      acc = fmaf(fcT[c1*64 + b], a2, acc);
    }

    out[b * OUTN + o] = acc + thrd[o * 64 + b];
}

extern "C" void kernel_launch(void* const* d_in, const int* in_sizes, int n_in,
                              void* d_out, int out_size, void* d_ws, size_t ws_size,
                              hipStream_t stream) {
    const float* x   = (const float*)d_in[0];
    const float* w1  = (const float*)d_in[1];
    const float* b1  = (const float*)d_in[2];
    const float* w2  = (const float*)d_in[3];
    const float* b2  = (const float*)d_in[4];
    const float* wm  = (const float*)d_in[5];
    const float* bm  = (const float*)d_in[6];
    const float* wc  = (const float*)d_in[7];
    const float* bcv = (const float*)d_in[8];
    const float* w3  = (const float*)d_in[9];
    const float* b3  = (const float*)d_in[10];
    float* out = (float*)d_out;

    // workspace layout (float offsets):
    //   h1T (bf16) | featp | featN | fc | thrd | w2frag
    float* ws    = (float*)d_ws;
    __bf16* h1T  = (__bf16*)ws;                      // 26,615,808 bf16 = 53.2 MB
    float* featp = ws + 13307904;                    // 28*64*64 = 114,688
    float* featN = ws + 13422592;                    // 4096
    float* fcv   = ws + 13426688;                    // 4096
    float* thrd  = ws + 13430784;                    // 64*1024 = 65,536
    __bf16* wfrg = (__bf16*)(ws + 13496320);         // 18,432 bf16

    conv1_kernel  <<<1568, 256, 0, stream>>>(x, w1, b1, h1T, w2, wfrg);
    conv2_kernel  <<<1792, 256, 0, stream>>>(h1T, wfrg, b2, featp);
    center2_kernel<<<64,   64,  0, stream>>>(featp, featN, fcv);
    third_kernel  <<<1024, 128, 0, stream>>>(fcv, w3, thrd);
    finale_kernel <<<256,  256, 0, stream>>>(featN, fcv, wm, bm, wc, bcv, b3, thrd, out);
}